// Round 10
// baseline (6206.604 us; speedup 1.0000x reference)
//
#include <hip/hip_runtime.h>

// ---------------- problem dims ----------------
#define S_LEN 128
#define BATCH 64
#define EDIM  512
#define PLEN  160
#define PDIM  512
#define HDIM  1024
#define G3    3072      // 3*H
#define NBLK  128       // 64 gate blocks + 64 attention blocks (1 per batch)
#define NTHR  256
#define PROWS 144       // post rows resident in LDS; rows 144..159 streamed from L2

typedef _Float16 half8v  __attribute__((ext_vector_type(8)));
typedef _Float16 half4v  __attribute__((ext_vector_type(4)));
typedef _Float16 half2v  __attribute__((ext_vector_type(2)));
typedef float    f32x4   __attribute__((ext_vector_type(4)));

// ---------------- workspace layout (bytes) ----------------
// ctrl: arrive 128 slots @ stride 32 at 0; qflag 32 slots @ stride 32 at 4096;
//       gensig 16 lines @ stride 256 at 8192
#define CTRL_UINTS 24576
#define OFF_CTRL ((size_t)0)                                  // 96 KiB
#define OFF_WIH  ((size_t)(CTRL_UINTS*4))                     // fp16 [3072][1024]
#define OFF_WHH  (OFF_WIH  + (size_t)G3*HDIM*2)               // fp16 [3072][1024]
#define OFF_WQH  (OFF_WHH  + (size_t)G3*HDIM*2)               // fp16 [512][1024]
#define OFF_INC  (OFF_WQH  + (size_t)PDIM*HDIM*2)             // fp16 [128][64][512]
#define OFF_POST (OFF_INC  + (size_t)S_LEN*BATCH*EDIM*2)      // fp16 [160][64][512]
#define OFF_HB   (OFF_POST + (size_t)PLEN*BATCH*PDIM*2)       // fp16 [2][64][1024] (double-buffered h)
#define OFF_QH   (OFF_HB   + (size_t)2*BATCH*HDIM*2)          // fp16 [64][512] query
#define OFF_CTX  (OFF_QH   + (size_t)BATCH*PDIM*2)            // fp16 [64][512]
// total ~33 MB

__global__ void init_ctrl(unsigned* u) {
    int i = threadIdx.x + blockIdx.x * blockDim.x;
    if (i < CTRL_UINTS) u[i] = 0u;
}

__device__ __forceinline__ float wave_sum(float v) {
    v += __shfl_xor(v, 32); v += __shfl_xor(v, 16); v += __shfl_xor(v, 8);
    v += __shfl_xor(v, 4);  v += __shfl_xor(v, 2);  v += __shfl_xor(v, 1);
    return v;
}
__device__ __forceinline__ float wave_max(float v) {
    v = fmaxf(v, __shfl_xor(v, 32)); v = fmaxf(v, __shfl_xor(v, 16));
    v = fmaxf(v, __shfl_xor(v, 8));  v = fmaxf(v, __shfl_xor(v, 4));
    v = fmaxf(v, __shfl_xor(v, 2));  v = fmaxf(v, __shfl_xor(v, 1));
    return v;
}

// coherent (L2-bypassing, write-through-to-L3) stores for cross-block data.
__device__ __forceinline__ void st2_coh(_Float16* p, _Float16 v) {
    union { _Float16 f; unsigned short u; } c; c.f = v;
    __hip_atomic_store((unsigned short*)p, c.u, __ATOMIC_RELAXED, __HIP_MEMORY_SCOPE_AGENT);
}
__device__ __forceinline__ void st4_coh(_Float16* p, half2v v) {
    union { half2v f; unsigned u; } c; c.f = v;
    __hip_atomic_store((unsigned*)p, c.u, __ATOMIC_RELAXED, __HIP_MEMORY_SCOPE_AGENT);
}

// Init-only one-hop grid barrier WITH full release/acquire (one-time cost).
__device__ __forceinline__ void gbar_acq(unsigned* arrive, unsigned& gen, int tid, int blk) {
    gen++;
    __syncthreads();
    if (tid == 0)
        __hip_atomic_store(&arrive[blk * 32], gen, __ATOMIC_RELEASE, __HIP_MEMORY_SCOPE_AGENT);
    if (tid < NBLK) {
        unsigned* fl = &arrive[tid * 32];
        while (__hip_atomic_load(fl, __ATOMIC_RELAXED, __HIP_MEMORY_SCOPE_AGENT) < gen)
            __builtin_amdgcn_s_sleep(1);
        __hip_atomic_load(fl, __ATOMIC_ACQUIRE, __HIP_MEMORY_SCOPE_AGENT);
    }
    __syncthreads();
}

// Time-loop grid barrier: AGGREGATED (R0 topology) + fully relaxed.
// Poll pressure: 1 poller per arrive line (block 0's threads), ~8 pollers per
// gensig line — ~254 total pollers vs the flat design's 16384. No release/
// acquire: data crosses via sc-atomics; __syncthreads' vmcnt(0) drain orders
// data stores before the arrive store.
__device__ __forceinline__ void gbar_agg(unsigned* ctrl, unsigned& gen, int tid, int blk) {
    gen++;
    __syncthreads();   // vmcnt(0): this block's coherent data stores are L3-complete
    unsigned* arrive = ctrl;               // 128 slots, stride 32
    unsigned* gensig = ctrl + 8192;        // 16 lines, stride 256
    if (blk == 0) {
        if (tid > 0 && tid < NBLK) {       // 127 pollers, one line each
            unsigned* fl = &arrive[tid * 32];
            while (__hip_atomic_load(fl, __ATOMIC_RELAXED, __HIP_MEMORY_SCOPE_AGENT) < gen)
                __builtin_amdgcn_s_sleep(1);
        }
        __syncthreads();
        if (tid < 16)
            __hip_atomic_store(&gensig[tid * 256], gen, __ATOMIC_RELAXED, __HIP_MEMORY_SCOPE_AGENT);
        __syncthreads();
    } else {
        if (tid == 0) {
            __hip_atomic_store(&arrive[blk * 32], gen, __ATOMIC_RELAXED, __HIP_MEMORY_SCOPE_AGENT);
            unsigned* sig = &gensig[(blk & 15) * 256];
            while (__hip_atomic_load(sig, __ATOMIC_RELAXED, __HIP_MEMORY_SCOPE_AGENT) < gen)
                __builtin_amdgcn_s_sleep(1);
        }
        __syncthreads();
    }
}

__device__ __forceinline__ void poll_ge_bk(unsigned* fl, unsigned target) {
    while (__hip_atomic_load(fl, __ATOMIC_RELAXED, __HIP_MEMORY_SCOPE_AGENT) < target)
        __builtin_amdgcn_s_sleep(2);   // backoff: ~64 pollers/line on qflag
}

// three output tiles sharing one A stream (r,z,n gate rows), plain A loads
__device__ __forceinline__ void mfma_acc3(f32x4& a0, f32x4& a1, f32x4& a2,
        const _Float16* __restrict__ A, int lda,
        const _Float16* __restrict__ B0, const _Float16* __restrict__ B1,
        const _Float16* __restrict__ B2, int ldb, int ksteps, int lane) {
    const _Float16* ap = A  + (size_t)(lane & 15) * lda + ((lane >> 4) << 3);
    const _Float16* p0 = B0 + (size_t)(lane & 15) * ldb + ((lane >> 4) << 3);
    const _Float16* p1 = B1 + (size_t)(lane & 15) * ldb + ((lane >> 4) << 3);
    const _Float16* p2 = B2 + (size_t)(lane & 15) * ldb + ((lane >> 4) << 3);
    #pragma unroll
    for (int ks = 0; ks < ksteps; ++ks) {
        half8v av = *(const half8v*)ap;
        a0 = __builtin_amdgcn_mfma_f32_16x16x32_f16(av, *(const half8v*)p0, a0, 0, 0, 0);
        a1 = __builtin_amdgcn_mfma_f32_16x16x32_f16(av, *(const half8v*)p1, a1, 0, 0, 0);
        a2 = __builtin_amdgcn_mfma_f32_16x16x32_f16(av, *(const half8v*)p2, a2, 0, 0, 0);
        ap += 32; p0 += 32; p1 += 32; p2 += 32;
    }
}

// same, A loaded coherently (L2-bypassing relaxed atomics) in 8-kstep bursts
__device__ __forceinline__ void mfma_acc3_coh(f32x4& a0, f32x4& a1, f32x4& a2,
        const _Float16* A, int lda,
        const _Float16* __restrict__ B0, const _Float16* __restrict__ B1,
        const _Float16* __restrict__ B2, int ldb, int ksteps, int lane) {
    const _Float16* ap = A  + (size_t)(lane & 15) * lda + ((lane >> 4) << 3);
    const _Float16* p0 = B0 + (size_t)(lane & 15) * ldb + ((lane >> 4) << 3);
    const _Float16* p1 = B1 + (size_t)(lane & 15) * ldb + ((lane >> 4) << 3);
    const _Float16* p2 = B2 + (size_t)(lane & 15) * ldb + ((lane >> 4) << 3);
    for (int c = 0; c < ksteps; c += 8) {
        unsigned long long u[16];
        #pragma unroll
        for (int i = 0; i < 8; ++i) {
            const unsigned long long* q = (const unsigned long long*)(ap + i*32);
            u[2*i]   = __hip_atomic_load(q,     __ATOMIC_RELAXED, __HIP_MEMORY_SCOPE_AGENT);
            u[2*i+1] = __hip_atomic_load(q + 1, __ATOMIC_RELAXED, __HIP_MEMORY_SCOPE_AGENT);
        }
        #pragma unroll
        for (int i = 0; i < 8; ++i) {
            union { unsigned long long w[2]; half8v v; } cv;
            cv.w[0] = u[2*i]; cv.w[1] = u[2*i+1];
            a0 = __builtin_amdgcn_mfma_f32_16x16x32_f16(cv.v, *(const half8v*)(p0 + i*32), a0, 0, 0, 0);
            a1 = __builtin_amdgcn_mfma_f32_16x16x32_f16(cv.v, *(const half8v*)(p1 + i*32), a1, 0, 0, 0);
            a2 = __builtin_amdgcn_mfma_f32_16x16x32_f16(cv.v, *(const half8v*)(p2 + i*32), a2, 0, 0, 0);
        }
        ap += 256; p0 += 256; p1 += 256; p2 += 256;
    }
}

// single-tile variant with coherent A (query producer)
__device__ __forceinline__ void mfma_acc_coh(f32x4& acc, const _Float16* A, int lda,
        const _Float16* __restrict__ Bb, int ldb, int ksteps, int lane) {
    const _Float16* ap = A  + (size_t)(lane & 15) * lda + ((lane >> 4) << 3);
    const _Float16* bp = Bb + (size_t)(lane & 15) * ldb + ((lane >> 4) << 3);
    for (int c = 0; c < ksteps; c += 8) {
        unsigned long long u[16];
        #pragma unroll
        for (int i = 0; i < 8; ++i) {
            const unsigned long long* q = (const unsigned long long*)(ap + i*32);
            u[2*i]   = __hip_atomic_load(q,     __ATOMIC_RELAXED, __HIP_MEMORY_SCOPE_AGENT);
            u[2*i+1] = __hip_atomic_load(q + 1, __ATOMIC_RELAXED, __HIP_MEMORY_SCOPE_AGENT);
        }
        #pragma unroll
        for (int i = 0; i < 8; ++i) {
            union { unsigned long long w[2]; half8v v; } cv;
            cv.w[0] = u[2*i]; cv.w[1] = u[2*i+1];
            acc = __builtin_amdgcn_mfma_f32_16x16x32_f16(cv.v, *(const half8v*)(bp + i*32), acc, 0, 0, 0);
        }
        ap += 256; bp += 256;
    }
}

__global__ __launch_bounds__(NTHR, 1) void gru_main(
    const float* __restrict__ incoming, const float* __restrict__ post,
    const float* __restrict__ h_init,   const float* __restrict__ w_ih,
    const float* __restrict__ w_hh,     const float* __restrict__ b_ih,
    const float* __restrict__ b_hh,     const float* __restrict__ wq,
    const float* __restrict__ bq,       const int* __restrict__ length,
    const int* __restrict__ post_length, float* __restrict__ out,
    char* __restrict__ ws)
{
    const int tid  = threadIdx.x;
    const int blk  = blockIdx.x;
    const int lane = tid & 63;
    const int wv   = tid >> 6;

    unsigned* ctrl   = (unsigned*)(ws + OFF_CTRL);
    unsigned* arrive = ctrl;                 // 128 x stride32 (init barrier + agg arrive)
    unsigned* qflag  = ctrl + 4096;          // 32 x stride32
    _Float16* wih_h  = (_Float16*)(ws + OFF_WIH);
    _Float16* whh_h  = (_Float16*)(ws + OFF_WHH);
    _Float16* wq_h   = (_Float16*)(ws + OFF_WQH);
    _Float16* inc_h  = (_Float16*)(ws + OFF_INC);
    _Float16* post_h = (_Float16*)(ws + OFF_POST);
    _Float16* hb     = (_Float16*)(ws + OFF_HB);            // [2][64][1024]
    _Float16* query_h= (_Float16*)(ws + OFF_QH);
    _Float16* ctx_h  = (_Float16*)(ws + OFF_CTX);

    __shared__ __align__(16) _Float16 s_post[PROWS * PDIM];   // 144 KB
    __shared__ __align__(16) _Float16 s_q[PDIM];              // 1 KB
    __shared__ float s_scores[PLEN];
    __shared__ float s_w[PLEN];
    __shared__ float s_bc[2];

    unsigned gen = 0;

    // ---------------- per-block loop-invariant hoists ----------------
    float bsr = 0.f, bsz = 0.f, bin_ = 0.f, bhn = 0.f, bqv = 0.f;
    float hp[4] = {0.f, 0.f, 0.f, 0.f};
    int lenb[4] = {0, 0, 0, 0};
    int j0 = 0, ab = 0, plen = 0;
    if (blk < 64) {                       // gate block: owns h-cols j0..j0+15
        j0 = blk * 16;
        const int j = j0 + (lane & 15);
        bsr  = b_ih[j] + b_hh[j];
        bsz  = b_ih[HDIM + j] + b_hh[HDIM + j];
        bin_ = b_ih[2*HDIM + j];
        bhn  = b_hh[2*HDIM + j];
        if (blk < 32) bqv = bq[blk*16 + (lane & 15)];   // query producer
        const float hi = h_init[j];
        const int r0 = wv*16 + ((lane >> 4) << 2);
        #pragma unroll
        for (int r = 0; r < 4; ++r) { hp[r] = hi; lenb[r] = length[r0 + r]; }
    } else {                              // attention block: owns batch ab
        ab = blk - 64;
        plen = post_length[ab];
    }

    // ---------------- init: fp32 -> fp16 conversions (grid-strided) ----------------
    {
        const int NV4_W    = G3*HDIM/4;
        const int NV4_WQ   = PDIM*HDIM/4;
        const int NV4_INC  = S_LEN*BATCH*EDIM/4;
        const int NV4_POST = PLEN*BATCH*PDIM/4;
        const int TOT = 2*NV4_W + NV4_WQ + NV4_INC + NV4_POST;
        for (int i = blk*NTHR + tid; i < TOT; i += NBLK*NTHR) {
            const float* s; _Float16* dp; int o;
            if (i < NV4_W)                          { s = w_ih;     dp = wih_h;  o = i; }
            else if (i < 2*NV4_W)                   { s = w_hh;     dp = whh_h;  o = i - NV4_W; }
            else if (i < 2*NV4_W + NV4_WQ)          { s = wq;       dp = wq_h;   o = i - 2*NV4_W; }
            else if (i < 2*NV4_W + NV4_WQ + NV4_INC){ s = incoming; dp = inc_h;  o = i - 2*NV4_W - NV4_WQ; }
            else                                    { s = post;     dp = post_h; o = i - 2*NV4_W - NV4_WQ - NV4_INC; }
            f32x4 v = *(const f32x4*)(s + (size_t)o*4);
            half4v hv4 = {(_Float16)v.x, (_Float16)v.y, (_Float16)v.z, (_Float16)v.w};
            *(half4v*)(dp + (size_t)o*4) = hv4;
        }
        for (int i = blk*NTHR + tid; i < BATCH*HDIM; i += NBLK*NTHR)
            hb[i] = (_Float16)h_init[i & (HDIM-1)];             // hb buffer 0
    }
    // attention blocks: stage post rows 0..PROWS-1 of own batch into LDS
    if (blk >= 64) {
        for (int i = tid; i < PROWS*PDIM; i += NTHR) {
            const int p = i >> 9, d = i & (PDIM-1);
            s_post[i] = (_Float16)post[((size_t)p*BATCH + ab)*PDIM + d];
        }
    }
    gbar_acq(arrive, gen, tid, blk);   // one-time: staging flushed to L3 + L2s inv'd

    // -------- time loop: qflag handshake + 2 aggregated relaxed barriers --------
    for (int t = 0; t < S_LEN; ++t) {
        f32x4 ghr = {0.f,0.f,0.f,0.f}, ghz = {0.f,0.f,0.f,0.f}, ghn_ = {0.f,0.f,0.f,0.f};
        f32x4 gir = {0.f,0.f,0.f,0.f}, giz = {0.f,0.f,0.f,0.f}, gin_ = {0.f,0.f,0.f,0.f};

        if (blk < 64) {
            const _Float16* hin = hb + (size_t)(t & 1) * BATCH * HDIM;
            // ==== A-phase gate: query FIRST (blocks 0..31, 16 cols each) ====
            if (blk < 32) {
                const int q0 = blk * 16;
                f32x4 qa = {0.f,0.f,0.f,0.f};
                mfma_acc_coh(qa, hin + (size_t)(wv*16)*HDIM, HDIM,
                             wq_h + (size_t)q0*HDIM, HDIM, HDIM/32, lane);
                const int q  = q0 + (lane & 15);
                const int r0 = wv*16 + ((lane >> 4) << 2);
                #pragma unroll
                for (int r = 0; r < 4; ++r)
                    st2_coh(&query_h[(size_t)(r0+r)*PDIM + q], (_Float16)(qa[r] + bqv));
                __syncthreads();   // vmcnt(0): query sc-stores L3-complete
                if (tid == 0)      // relaxed flag (no wbl2)
                    __hip_atomic_store(&qflag[blk * 32], (unsigned)(t+1),
                                       __ATOMIC_RELAXED, __HIP_MEMORY_SCOPE_AGENT);
            }
            // gh = h@Whh^T (coherent A burst); gi_x = x_t@Wih^T (plain, L2-hot)
            mfma_acc3_coh(ghr, ghz, ghn_, hin + (size_t)(wv*16)*HDIM, HDIM,
                          whh_h + (size_t)j0*HDIM,
                          whh_h + (size_t)(HDIM + j0)*HDIM,
                          whh_h + (size_t)(2*HDIM + j0)*HDIM, HDIM, HDIM/32, lane);
            mfma_acc3(gir, giz, gin_, inc_h + ((size_t)t*BATCH + wv*16)*EDIM, EDIM,
                      wih_h + (size_t)j0*HDIM,
                      wih_h + (size_t)(HDIM + j0)*HDIM,
                      wih_h + (size_t)(2*HDIM + j0)*HDIM, HDIM, EDIM/32, lane);
        } else {
            // ==== A-phase attention for batch ab ====
            // streamed post rows (immutable, plain loads)
            half8v srow[4];
            #pragma unroll
            for (int i = 0; i < 4; ++i)
                srow[i] = *(const half8v*)(post_h +
                            ((size_t)(PROWS + wv + 4*i)*BATCH + ab)*PDIM + lane*8);
            // wait for the 32 query producers, then coherent-read own query row
            if (tid < 32) poll_ge_bk(&qflag[tid * 32], (unsigned)(t+1));
            __syncthreads();
            if (tid < PDIM/4) {    // 128 threads x 8B = 1 KB
                const unsigned long long* qin =
                    (const unsigned long long*)(query_h + (size_t)ab*PDIM);
                ((unsigned long long*)s_q)[tid] =
                    __hip_atomic_load(qin + tid, __ATOMIC_RELAXED, __HIP_MEMORY_SCOPE_AGENT);
            }
            __syncthreads();

            // scores = post . query
            const half8v qv = *(const half8v*)&s_q[lane*8];
            #pragma unroll 2
            for (int p = wv; p < PROWS; p += 4) {
                const half8v pv = *(const half8v*)&s_post[(size_t)p*PDIM + lane*8];
                float sd = 0.f;
                #pragma unroll
                for (int jj = 0; jj < 8; ++jj) sd += (float)pv[jj] * (float)qv[jj];
                sd = wave_sum(sd);
                if (lane == 0) s_scores[p] = sd;
            }
            #pragma unroll
            for (int i = 0; i < 4; ++i) {
                const half8v pv = srow[i];
                float sd = 0.f;
                #pragma unroll
                for (int jj = 0; jj < 8; ++jj) sd += (float)pv[jj] * (float)qv[jj];
                sd = wave_sum(sd);
                if (lane == 0) s_scores[PROWS + wv + 4*i] = sd;
            }
            __syncthreads();
            if (wv == 0) {
                float m = -1e30f;
                for (int p = lane; p < plen; p += 64) m = fmaxf(m, s_scores[p]);
                m = wave_max(m);
                if (lane == 0) s_bc[0] = m;
            }
            __syncthreads();
            const float mx = s_bc[0];
            if (tid < PLEN) s_w[tid] = (tid < plen) ? __expf(s_scores[tid] - mx) : 0.f;
            __syncthreads();
            if (wv == 0) {
                float ss = 0.f;
                for (int p = lane; p < PLEN; p += 64) ss += s_w[p];
                ss = wave_sum(ss);
                if (lane == 0) s_bc[1] = 1.f / ss;
            }
            __syncthreads();
            const float inv_den = s_bc[1];
            // ctx[d0,d0+1] -> coherent 4B store (write-through to L3)
            const int d0 = tid << 1;
            float ca = 0.f, cb = 0.f;
            #pragma unroll 4
            for (int p = 0; p < PROWS; ++p) {
                const half2v pv2 = *(const half2v*)&s_post[(size_t)p*PDIM + d0];
                const float wp = s_w[p];
                ca += wp * (float)pv2[0];
                cb += wp * (float)pv2[1];
            }
            #pragma unroll 4
            for (int p = PROWS; p < PLEN; ++p) {
                const half2v pv2 = *(const half2v*)(post_h + ((size_t)p*BATCH + ab)*PDIM + d0);
                const float wp = s_w[p];
                ca += wp * (float)pv2[0];
                cb += wp * (float)pv2[1];
            }
            half2v cv; cv[0] = (_Float16)(ca * inv_den); cv[1] = (_Float16)(cb * inv_den);
            st4_coh(&ctx_h[(size_t)ab*PDIM + d0], cv);
        }

        gbar_agg(ctrl, gen, tid, blk);   // barrier W: ctx L3-visible (aggregated, relaxed)

        if (blk < 64) {
            // ==== B-phase gate: gi += ctx@Wih[:, 512:]^T (coherent A), h update ====
            mfma_acc3_coh(gir, giz, gin_, ctx_h + (size_t)(wv*16)*PDIM, PDIM,
                          wih_h + (size_t)j0*HDIM + PDIM,
                          wih_h + (size_t)(HDIM + j0)*HDIM + PDIM,
                          wih_h + (size_t)(2*HDIM + j0)*HDIM + PDIM, HDIM, PDIM/32, lane);

            _Float16* hout = hb + (size_t)((t + 1) & 1) * BATCH * HDIM;
            const int j  = j0 + (lane & 15);
            const int r0 = wv*16 + ((lane >> 4) << 2);
            #pragma unroll
            for (int r = 0; r < 4; ++r) {
                const int b = r0 + r;
                const float rg = 1.f / (1.f + __expf(-(gir[r] + ghr[r] + bsr)));
                const float zg = 1.f / (1.f + __expf(-(giz[r] + ghz[r] + bsz)));
                const float e2 = __expf(2.f * ((gin_[r] + bin_) + rg * (ghn_[r] + bhn)));
                const float ng = 1.f - 2.f / (e2 + 1.f);        // tanh
                float hv = (1.f - zg) * ng + zg * hp[r];
                if (lenb[r] <= t) hv = 0.f;
                hp[r] = hv;
                out[(size_t)t*BATCH*HDIM + (size_t)b*HDIM + j] = hv;   // plain (end-of-kernel flush)
                st2_coh(&hout[(size_t)b*HDIM + j], (_Float16)hv);      // coherent: L3 write-through
                if (t == S_LEN - 1)
                    out[(size_t)S_LEN*BATCH*HDIM + (size_t)b*HDIM + j] = hv;  // h_last
            }
        }
        // barrier H: h(t+1) L3-visible; last step skips
        if (t < S_LEN - 1) gbar_agg(ctrl, gen, tid, blk);
    }
}

extern "C" void kernel_launch(void* const* d_in, const int* in_sizes, int n_in,
                              void* d_out, int out_size, void* d_ws, size_t ws_size,
                              hipStream_t stream) {
    (void)in_sizes; (void)n_in; (void)out_size; (void)ws_size;
    const float* incoming    = (const float*)d_in[0];
    const float* post        = (const float*)d_in[1];
    const float* h_init      = (const float*)d_in[2];
    const float* w_ih        = (const float*)d_in[3];
    const float* w_hh        = (const float*)d_in[4];
    const float* b_ih        = (const float*)d_in[5];
    const float* b_hh        = (const float*)d_in[6];
    const float* wq          = (const float*)d_in[7];
    const float* bq          = (const float*)d_in[8];
    const int*   length      = (const int*)d_in[9];
    const int*   post_length = (const int*)d_in[10];
    float* out = (float*)d_out;

    init_ctrl<<<96, 256, 0, stream>>>((unsigned*)d_ws);
    gru_main<<<NBLK, NTHR, 0, stream>>>(incoming, post, h_init, w_ih, w_hh, b_ih, b_hh,
                                        wq, bq, length, post_length, out, (char*)d_ws);
}

// Round 11
// 5777.930 us; speedup vs baseline: 1.0742x; 1.0742x over previous
//
#include <hip/hip_runtime.h>

// ---------------- problem dims ----------------
#define S_LEN 128
#define BATCH 64
#define EDIM  512
#define PLEN  160
#define PDIM  512
#define HDIM  1024
#define G3    3072      // 3*H
#define NBLK  128       // 64 gate blocks + 64 attention blocks (1 per batch)
#define NTHR  256
#define PROWS 144       // post rows resident in LDS; rows 144..159 streamed from L2

typedef _Float16 half8v  __attribute__((ext_vector_type(8)));
typedef _Float16 half4v  __attribute__((ext_vector_type(4)));
typedef _Float16 half2v  __attribute__((ext_vector_type(2)));
typedef float    f32x4   __attribute__((ext_vector_type(4)));

// ---------------- workspace layout (bytes) ----------------
// ctrl: arrive flags 128 slots @ stride 32 uints; qflag 32 slots @ stride 32
#define CTRL_UINTS 24576
#define OFF_CTRL ((size_t)0)                                  // 96 KiB
#define OFF_WIH  ((size_t)(CTRL_UINTS*4))                     // fp16 [3072][1024]
#define OFF_WHH  (OFF_WIH  + (size_t)G3*HDIM*2)               // fp16 [3072][1024]
#define OFF_WQH  (OFF_WHH  + (size_t)G3*HDIM*2)               // fp16 [512][1024]
#define OFF_INC  (OFF_WQH  + (size_t)PDIM*HDIM*2)             // fp16 [128][64][512]
#define OFF_POST (OFF_INC  + (size_t)S_LEN*BATCH*EDIM*2)      // fp16 [160][64][512]
#define OFF_HH   (OFF_POST + (size_t)PLEN*BATCH*PDIM*2)       // fp16 [64][1024]
#define OFF_QH   (OFF_HH   + (size_t)BATCH*HDIM*2)            // fp16 [64][512]
#define OFF_CTX  (OFF_QH   + (size_t)BATCH*PDIM*2)            // fp16 [64][512]
// total ~31 MB

__global__ void init_ctrl(unsigned* u) {
    int i = threadIdx.x + blockIdx.x * blockDim.x;
    if (i < CTRL_UINTS) u[i] = 0u;
}

__device__ __forceinline__ float wave_sum(float v) {
    v += __shfl_xor(v, 32); v += __shfl_xor(v, 16); v += __shfl_xor(v, 8);
    v += __shfl_xor(v, 4);  v += __shfl_xor(v, 2);  v += __shfl_xor(v, 1);
    return v;
}
__device__ __forceinline__ float wave_max(float v) {
    v = fmaxf(v, __shfl_xor(v, 32)); v = fmaxf(v, __shfl_xor(v, 16));
    v = fmaxf(v, __shfl_xor(v, 8));  v = fmaxf(v, __shfl_xor(v, 4));
    v = fmaxf(v, __shfl_xor(v, 2));  v = fmaxf(v, __shfl_xor(v, 1));
    return v;
}

// One-hop grid barrier (R4 semantics: release store + relaxed BUSY poll +
// per-thread acquire). The ONLY change vs R4: no s_sleep — hot spin keeps
// waves issuing (clocks up) and catches the flag within one load RT.
__device__ __forceinline__ void gbar(unsigned* arrive, unsigned& gen, int tid, int blk) {
    gen++;
    __syncthreads();   // drains vmcnt before s_barrier -> all block stores in L2
    if (tid == 0)
        __hip_atomic_store(&arrive[blk * 32], gen, __ATOMIC_RELEASE, __HIP_MEMORY_SCOPE_AGENT);
    if (tid < NBLK) {
        unsigned* fl = &arrive[tid * 32];
        while (__hip_atomic_load(fl, __ATOMIC_RELAXED, __HIP_MEMORY_SCOPE_AGENT) < gen) { }
        __hip_atomic_load(fl, __ATOMIC_ACQUIRE, __HIP_MEMORY_SCOPE_AGENT);
    }
    __syncthreads();
}

// one 16x16 output tile accumulation: D[m,n] += sum_k A[m,k] * W[n,k]
__device__ __forceinline__ void mfma_acc(f32x4& acc, const _Float16* __restrict__ A, int lda,
                                         const _Float16* __restrict__ Bb, int ldb,
                                         int ksteps, int lane) {
    const _Float16* ap = A  + (size_t)(lane & 15) * lda + ((lane >> 4) << 3);
    const _Float16* bp = Bb + (size_t)(lane & 15) * ldb + ((lane >> 4) << 3);
    #pragma unroll
    for (int ks = 0; ks < ksteps; ++ks) {
        half8v av = *(const half8v*)ap;
        half8v bv = *(const half8v*)bp;
        acc = __builtin_amdgcn_mfma_f32_16x16x32_f16(av, bv, acc, 0, 0, 0);
        ap += 32; bp += 32;
    }
}

// three output tiles sharing one A stream (r,z,n gate rows)
__device__ __forceinline__ void mfma_acc3(f32x4& a0, f32x4& a1, f32x4& a2,
        const _Float16* __restrict__ A, int lda,
        const _Float16* __restrict__ B0, const _Float16* __restrict__ B1,
        const _Float16* __restrict__ B2, int ldb, int ksteps, int lane) {
    const _Float16* ap = A  + (size_t)(lane & 15) * lda + ((lane >> 4) << 3);
    const _Float16* p0 = B0 + (size_t)(lane & 15) * ldb + ((lane >> 4) << 3);
    const _Float16* p1 = B1 + (size_t)(lane & 15) * ldb + ((lane >> 4) << 3);
    const _Float16* p2 = B2 + (size_t)(lane & 15) * ldb + ((lane >> 4) << 3);
    #pragma unroll
    for (int ks = 0; ks < ksteps; ++ks) {
        half8v av = *(const half8v*)ap;
        a0 = __builtin_amdgcn_mfma_f32_16x16x32_f16(av, *(const half8v*)p0, a0, 0, 0, 0);
        a1 = __builtin_amdgcn_mfma_f32_16x16x32_f16(av, *(const half8v*)p1, a1, 0, 0, 0);
        a2 = __builtin_amdgcn_mfma_f32_16x16x32_f16(av, *(const half8v*)p2, a2, 0, 0, 0);
        ap += 32; p0 += 32; p1 += 32; p2 += 32;
    }
}

__global__ __launch_bounds__(NTHR, 1) void gru_main(
    const float* __restrict__ incoming, const float* __restrict__ post,
    const float* __restrict__ h_init,   const float* __restrict__ w_ih,
    const float* __restrict__ w_hh,     const float* __restrict__ b_ih,
    const float* __restrict__ b_hh,     const float* __restrict__ wq,
    const float* __restrict__ bq,       const int* __restrict__ length,
    const int* __restrict__ post_length, float* __restrict__ out,
    char* __restrict__ ws)
{
    const int tid  = threadIdx.x;
    const int blk  = blockIdx.x;
    const int lane = tid & 63;
    const int wv   = tid >> 6;

    unsigned* arrive = (unsigned*)(ws + OFF_CTRL);        // 128 x stride32
    unsigned* qflag  = (unsigned*)(ws + OFF_CTRL) + 4096; // 32 x stride32
    _Float16* wih_h  = (_Float16*)(ws + OFF_WIH);
    _Float16* whh_h  = (_Float16*)(ws + OFF_WHH);
    _Float16* wq_h   = (_Float16*)(ws + OFF_WQH);
    _Float16* inc_h  = (_Float16*)(ws + OFF_INC);
    _Float16* post_h = (_Float16*)(ws + OFF_POST);
    _Float16* h_h    = (_Float16*)(ws + OFF_HH);
    _Float16* query_h= (_Float16*)(ws + OFF_QH);
    _Float16* ctx_h  = (_Float16*)(ws + OFF_CTX);

    __shared__ __align__(16) _Float16 s_post[PROWS * PDIM];   // 144 KB
    __shared__ __align__(16) _Float16 s_q[PDIM];              // 1 KB
    __shared__ float s_scores[PLEN];
    __shared__ float s_w[PLEN];
    __shared__ float s_bc[2];

    unsigned gen = 0;

    // ---------------- per-block loop-invariant hoists ----------------
    float bsr = 0.f, bsz = 0.f, bin_ = 0.f, bhn = 0.f, bqv = 0.f;
    float hp[4] = {0.f, 0.f, 0.f, 0.f};
    int lenb[4] = {0, 0, 0, 0};
    int j0 = 0, ab = 0, plen = 0;
    if (blk < 64) {                       // gate block: owns h-cols j0..j0+15
        j0 = blk * 16;
        const int j = j0 + (lane & 15);
        bsr  = b_ih[j] + b_hh[j];
        bsz  = b_ih[HDIM + j] + b_hh[HDIM + j];
        bin_ = b_ih[2*HDIM + j];
        bhn  = b_hh[2*HDIM + j];
        if (blk < 32) bqv = bq[blk*16 + (lane & 15)];   // query producer
        const float hi = h_init[j];
        const int r0 = wv*16 + ((lane >> 4) << 2);
        #pragma unroll
        for (int r = 0; r < 4; ++r) { hp[r] = hi; lenb[r] = length[r0 + r]; }
    } else {                              // attention block: owns batch ab
        ab = blk - 64;
        plen = post_length[ab];
    }

    // ---------------- init: fp32 -> fp16 conversions (grid-strided) ----------------
    {
        const int NV4_W    = G3*HDIM/4;
        const int NV4_WQ   = PDIM*HDIM/4;
        const int NV4_INC  = S_LEN*BATCH*EDIM/4;
        const int NV4_POST = PLEN*BATCH*PDIM/4;
        const int TOT = 2*NV4_W + NV4_WQ + NV4_INC + NV4_POST;
        for (int i = blk*NTHR + tid; i < TOT; i += NBLK*NTHR) {
            const float* s; _Float16* dp; int o;
            if (i < NV4_W)                          { s = w_ih;     dp = wih_h;  o = i; }
            else if (i < 2*NV4_W)                   { s = w_hh;     dp = whh_h;  o = i - NV4_W; }
            else if (i < 2*NV4_W + NV4_WQ)          { s = wq;       dp = wq_h;   o = i - 2*NV4_W; }
            else if (i < 2*NV4_W + NV4_WQ + NV4_INC){ s = incoming; dp = inc_h;  o = i - 2*NV4_W - NV4_WQ; }
            else                                    { s = post;     dp = post_h; o = i - 2*NV4_W - NV4_WQ - NV4_INC; }
            f32x4 v = *(const f32x4*)(s + (size_t)o*4);
            half4v hv4 = {(_Float16)v.x, (_Float16)v.y, (_Float16)v.z, (_Float16)v.w};
            *(half4v*)(dp + (size_t)o*4) = hv4;
        }
        for (int i = blk*NTHR + tid; i < BATCH*HDIM; i += NBLK*NTHR)
            h_h[i] = (_Float16)h_init[i & (HDIM-1)];
    }
    // attention blocks: stage post rows 0..PROWS-1 of own batch into LDS
    if (blk >= 64) {
        for (int i = tid; i < PROWS*PDIM; i += NTHR) {
            const int p = i >> 9, d = i & (PDIM-1);
            s_post[i] = (_Float16)post[((size_t)p*BATCH + ab)*PDIM + d];
        }
    }
    gbar(arrive, gen, tid, blk);   // weights/inc/post/h ready

    // ---------------- time loop: 2 grid barriers + qflag handshake per step ----------------
    for (int t = 0; t < S_LEN; ++t) {
        f32x4 ghr = {0.f,0.f,0.f,0.f}, ghz = {0.f,0.f,0.f,0.f}, ghn_ = {0.f,0.f,0.f,0.f};
        f32x4 gir = {0.f,0.f,0.f,0.f}, giz = {0.f,0.f,0.f,0.f}, gin_ = {0.f,0.f,0.f,0.f};

        if (blk < 64) {
            // ==== P1 gate: query FIRST (blocks 0..31), release flag, then gh/gi_x ====
            if (blk < 32) {
                const int q0 = blk * 16;
                f32x4 qa = {0.f,0.f,0.f,0.f};
                mfma_acc(qa, h_h + (size_t)(wv*16)*HDIM, HDIM,
                         wq_h + (size_t)q0*HDIM, HDIM, HDIM/32, lane);
                const int q  = q0 + (lane & 15);
                const int r0 = wv*16 + ((lane >> 4) << 2);
                #pragma unroll
                for (int r = 0; r < 4; ++r)
                    query_h[(size_t)(r0+r)*PDIM + q] = (_Float16)(qa[r] + bqv);
                __syncthreads();   // all waves' query stores drained (vmcnt0)
                if (tid == 0)
                    __hip_atomic_store(&qflag[blk * 32], (unsigned)(t+1),
                                       __ATOMIC_RELEASE, __HIP_MEMORY_SCOPE_AGENT);
            }
            // gh = h@Whh^T (r,z,n); gi_x = x_t@Wih[:, :512]^T — accumulators stay
            // in registers across barrier W (no staging buffers)
            mfma_acc3(ghr, ghz, ghn_, h_h + (size_t)(wv*16)*HDIM, HDIM,
                      whh_h + (size_t)j0*HDIM,
                      whh_h + (size_t)(HDIM + j0)*HDIM,
                      whh_h + (size_t)(2*HDIM + j0)*HDIM, HDIM, HDIM/32, lane);
            mfma_acc3(gir, giz, gin_, inc_h + ((size_t)t*BATCH + wv*16)*EDIM, EDIM,
                      wih_h + (size_t)j0*HDIM,
                      wih_h + (size_t)(HDIM + j0)*HDIM,
                      wih_h + (size_t)(2*HDIM + j0)*HDIM, HDIM, EDIM/32, lane);
        } else {
            // ==== P1 attention for batch ab: scores = post . query, softmax, ctx ====
            // prefetch streamed rows (independent of query) before the flag wait
            half8v srow[4];
            #pragma unroll
            for (int i = 0; i < 4; ++i)
                srow[i] = *(const half8v*)(post_h +
                            ((size_t)(PROWS + wv + 4*i)*BATCH + ab)*PDIM + lane*8);
            // wait for query producers (32 flags, written early in gate P1) — hot spin
            if (tid < 32) {
                unsigned* fl = &qflag[tid * 32];
                while (__hip_atomic_load(fl, __ATOMIC_RELAXED, __HIP_MEMORY_SCOPE_AGENT) < (unsigned)(t+1)) { }
                __hip_atomic_load(fl, __ATOMIC_ACQUIRE, __HIP_MEMORY_SCOPE_AGENT);
            }
            __syncthreads();
            if (tid < PDIM/8)
                *(half8v*)&s_q[tid*8] = *(const half8v*)&query_h[(size_t)ab*PDIM + tid*8];
            __syncthreads();
            const half8v qv = *(const half8v*)&s_q[lane*8];
            #pragma unroll 2
            for (int p = wv; p < PROWS; p += 4) {
                const half8v pv = *(const half8v*)&s_post[(size_t)p*PDIM + lane*8];
                float sd = 0.f;
                #pragma unroll
                for (int jj = 0; jj < 8; ++jj) sd += (float)pv[jj] * (float)qv[jj];
                sd = wave_sum(sd);
                if (lane == 0) s_scores[p] = sd;
            }
            #pragma unroll
            for (int i = 0; i < 4; ++i) {
                const half8v pv = srow[i];
                float sd = 0.f;
                #pragma unroll
                for (int jj = 0; jj < 8; ++jj) sd += (float)pv[jj] * (float)qv[jj];
                sd = wave_sum(sd);
                if (lane == 0) s_scores[PROWS + wv + 4*i] = sd;
            }
            __syncthreads();
            if (wv == 0) {
                float m = -1e30f;
                for (int p = lane; p < plen; p += 64) m = fmaxf(m, s_scores[p]);
                m = wave_max(m);
                if (lane == 0) s_bc[0] = m;
            }
            __syncthreads();
            const float mx = s_bc[0];
            if (tid < PLEN) s_w[tid] = (tid < plen) ? __expf(s_scores[tid] - mx) : 0.f;
            __syncthreads();
            if (wv == 0) {
                float ss = 0.f;
                for (int p = lane; p < PLEN; p += 64) ss += s_w[p];
                ss = wave_sum(ss);
                if (lane == 0) s_bc[1] = 1.f / ss;
            }
            __syncthreads();
            const float inv_den = s_bc[1];
            // ctx[d0,d0+1]: LDS rows then streamed rows (L1/L2-hot from score pass)
            const int d0 = tid << 1;
            float ca = 0.f, cb = 0.f;
            #pragma unroll 4
            for (int p = 0; p < PROWS; ++p) {
                const half2v pv2 = *(const half2v*)&s_post[(size_t)p*PDIM + d0];
                const float wp = s_w[p];
                ca += wp * (float)pv2[0];
                cb += wp * (float)pv2[1];
            }
            #pragma unroll 4
            for (int p = PROWS; p < PLEN; ++p) {
                const half2v pv2 = *(const half2v*)(post_h + ((size_t)p*BATCH + ab)*PDIM + d0);
                const float wp = s_w[p];
                ca += wp * (float)pv2[0];
                cb += wp * (float)pv2[1];
            }
            half2v cv; cv[0] = (_Float16)(ca * inv_den); cv[1] = (_Float16)(cb * inv_den);
            *(half2v*)&ctx_h[(size_t)ab*PDIM + d0] = cv;
        }
        gbar(arrive, gen, tid, blk);   // barrier W: ctx ready

        if (blk < 64) {
            // ==== P2 gate: gi += ctx@Wih[:, 512:]^T, gate math, h update ====
            mfma_acc3(gir, giz, gin_, ctx_h + (size_t)(wv*16)*PDIM, PDIM,
                      wih_h + (size_t)j0*HDIM + PDIM,
                      wih_h + (size_t)(HDIM + j0)*HDIM + PDIM,
                      wih_h + (size_t)(2*HDIM + j0)*HDIM + PDIM, HDIM, PDIM/32, lane);
            const int j  = j0 + (lane & 15);
            const int r0 = wv*16 + ((lane >> 4) << 2);
            #pragma unroll
            for (int r = 0; r < 4; ++r) {
                const int b = r0 + r;
                const float rg = 1.f / (1.f + __expf(-(gir[r] + ghr[r] + bsr)));
                const float zg = 1.f / (1.f + __expf(-(giz[r] + ghz[r] + bsz)));
                const float e2 = __expf(2.f * ((gin_[r] + bin_) + rg * (ghn_[r] + bhn)));
                const float ng = 1.f - 2.f / (e2 + 1.f);        // tanh
                float hv = (1.f - zg) * ng + zg * hp[r];
                if (lenb[r] <= t) hv = 0.f;
                hp[r] = hv;
                out[(size_t)t*BATCH*HDIM + (size_t)b*HDIM + j] = hv;
                h_h[(size_t)b*HDIM + j] = (_Float16)hv;
                if (t == S_LEN - 1)
                    out[(size_t)S_LEN*BATCH*HDIM + (size_t)b*HDIM + j] = hv;  // h_last
            }
        }
        if (t < S_LEN - 1) gbar(arrive, gen, tid, blk);   // barrier H: h ready
    }
}

extern "C" void kernel_launch(void* const* d_in, const int* in_sizes, int n_in,
                              void* d_out, int out_size, void* d_ws, size_t ws_size,
                              hipStream_t stream) {
    (void)in_sizes; (void)n_in; (void)out_size; (void)ws_size;
    const float* incoming    = (const float*)d_in[0];
    const float* post        = (const float*)d_in[1];
    const float* h_init      = (const float*)d_in[2];
    const float* w_ih        = (const float*)d_in[3];
    const float* w_hh        = (const float*)d_in[4];
    const float* b_ih        = (const float*)d_in[5];
    const float* b_hh        = (const float*)d_in[6];
    const float* wq          = (const float*)d_in[7];
    const float* bq          = (const float*)d_in[8];
    const int*   length      = (const int*)d_in[9];
    const int*   post_length = (const int*)d_in[10];
    float* out = (float*)d_out;

    init_ctrl<<<96, 256, 0, stream>>>((unsigned*)d_ws);
    gru_main<<<NBLK, NTHR, 0, stream>>>(incoming, post, h_init, w_ih, w_hh, b_ih, b_hh,
                                        wq, bq, length, post_length, out, (char*)d_ws);
}